// Round 11
// baseline (69.759 us; speedup 1.0000x reference)
//
#include <hip/hip_runtime.h>

#define LOG2E 1.44269504088896340736f

__device__ __forceinline__ float fexp2(float x){
#if __has_builtin(__builtin_amdgcn_exp2f)
  return __builtin_amdgcn_exp2f(x);
#else
  return exp2f(x);
#endif
}
__device__ __forceinline__ float frcp(float x){
#if __has_builtin(__builtin_amdgcn_rcpf)
  return __builtin_amdgcn_rcpf(x);
#else
  return 1.0f/x;
#endif
}
__device__ __forceinline__ float tanh_fast(float x){
  float e = fexp2(x * (2.0f*LOG2E));
  return 1.0f - 2.0f*frcp(e + 1.0f);
}
__device__ __forceinline__ float4 fma4(float s, float4 w, float4 a){
  a.x = fmaf(s,w.x,a.x); a.y = fmaf(s,w.y,a.y);
  a.z = fmaf(s,w.z,a.z); a.w = fmaf(s,w.w,a.w);
  return a;
}

// Rank-3 attention. 256-thread block, wave = branch, NB=4 batches/block
// (grid 1024 — R6's proven best block shape), zero barriers.
// R9 lean-LDS: broadcast only raw (xk,yk) = 8 B/k; per-row coefficients
// (A,B,C) = M^T g(q) in registers; S[q,k] = A*xk + B*yk + C.
// R10: the two batches of a pair are INTERLEAVED in the k-loop — per
// float4-iter: 2 independent ds_read_b128 + 40 VALU + 8 exp across 4
// independent chains, hiding exp (16 cyc/wave64, measured R9) and DS
// latency under other chains' VALU at only 4 waves/SIMD.
// h = mean_q(Ex/E)*wv0 + mean_q(Ey/E)*wv1 + vb. Lane owns rows lane, lane+64.
template<int DQ, int DV, int NB>
__device__ __forceinline__ void branch_run(
    const float* __restrict__ state, int b0, int n0,
    const float* __restrict__ W, const float* __restrict__ bias,
    float2* __restrict__ sg0, float2* __restrict__ sg1,
    int hoff, float* __restrict__ hbuf, int lane)
{
  const int D = 4*DQ;
  const float qs = LOG2E * (DQ==8 ? 0.35355339059327373f : 0.25f); // log2e/sqrt(dk)

  // M = Aq Ak^T * qs — once per block, uniform operands.
  float M00=0,M01=0,M02=0,M10=0,M11=0,M12=0,M20=0,M21=0,M22=0;
  #pragma unroll
  for (int d=0; d<DQ; ++d) {
    float aq0 = W[d], aq1 = W[D+d], aq2 = bias[d];
    float ak0 = W[DQ+d], ak1 = W[D+DQ+d], ak2 = bias[DQ+d];
    M00 = fmaf(aq0,ak0,M00); M01 = fmaf(aq0,ak1,M01); M02 = fmaf(aq0,ak2,M02);
    M10 = fmaf(aq1,ak0,M10); M11 = fmaf(aq1,ak1,M11); M12 = fmaf(aq1,ak2,M12);
    M20 = fmaf(aq2,ak0,M20); M21 = fmaf(aq2,ak1,M21); M22 = fmaf(aq2,ak2,M22);
  }
  M00*=qs; M01*=qs; M02*=qs; M10*=qs; M11*=qs; M12*=qs; M20*=qs; M21*=qs; M22*=qs;

  float wv0 = 0.f, wv1 = 0.f, vb = 0.f;
  if (lane < DV) { wv0 = W[2*DQ+lane]; wv1 = W[D+2*DQ+lane]; vb = bias[2*DQ+lane]; }

  #pragma unroll 1
  for (int e = 0; e < NB; e += 2) {
    const int bA = b0 + e, bB = b0 + e + 1;
    const float* spA = state + ((size_t)bA*512 + (size_t)(n0 + lane))*3;
    const float* spB = state + ((size_t)bB*512 + (size_t)(n0 + lane))*3;
    float xA0 = spA[0],   yA0 = spA[1];
    float xA1 = spA[192], yA1 = spA[193];
    float xB0 = spB[0],   yB0 = spB[1];
    float xB1 = spB[192], yB1 = spB[193];

    // stage raw (x,y) for own k's, both batches (same-wave, lgkmcnt only)
    float2 t;
    t.x=xA0; t.y=yA0; sg0[lane]    = t;
    t.x=xA1; t.y=yA1; sg0[lane+64] = t;
    t.x=xB0; t.y=yB0; sg1[lane]    = t;
    t.x=xB1; t.y=yB1; sg1[lane+64] = t;

    // per-row query coefficients (A,B,C) = M^T g(row), 4 rows
    float AA0 = fmaf(xA0,M00, fmaf(yA0,M10, M20));
    float BA0 = fmaf(xA0,M01, fmaf(yA0,M11, M21));
    float CA0 = fmaf(xA0,M02, fmaf(yA0,M12, M22));
    float AA1 = fmaf(xA1,M00, fmaf(yA1,M10, M20));
    float BA1 = fmaf(xA1,M01, fmaf(yA1,M11, M21));
    float CA1 = fmaf(xA1,M02, fmaf(yA1,M12, M22));
    float AB0 = fmaf(xB0,M00, fmaf(yB0,M10, M20));
    float BB0 = fmaf(xB0,M01, fmaf(yB0,M11, M21));
    float CB0 = fmaf(xB0,M02, fmaf(yB0,M12, M22));
    float AB1 = fmaf(xB1,M00, fmaf(yB1,M10, M20));
    float BB1 = fmaf(xB1,M01, fmaf(yB1,M11, M21));
    float CB1 = fmaf(xB1,M02, fmaf(yB1,M12, M22));

    float EA0=0.f, ExA0=0.f, EyA0=0.f, EA1=0.f, ExA1=0.f, EyA1=0.f;
    float EB0=0.f, ExB0=0.f, EyB0=0.f, EB1=0.f, ExB1=0.f, EyB1=0.f;
    const float4* G0 = (const float4*)sg0;   // (x[2p],y[2p],x[2p+1],y[2p+1])
    const float4* G1 = (const float4*)sg1;
    #pragma unroll 2
    for (int p = 0; p < 64; ++p) {
      float4 ga = G0[p];
      float4 gb = G1[p];
      {  // batch A, k = 2p
        float s0 = fmaf(AA0,ga.x, fmaf(BA0,ga.y, CA0));
        float s1 = fmaf(AA1,ga.x, fmaf(BA1,ga.y, CA1));
        float e0 = fexp2(s0), e1 = fexp2(s1);
        EA0 += e0;  ExA0 = fmaf(e0,ga.x,ExA0);  EyA0 = fmaf(e0,ga.y,EyA0);
        EA1 += e1;  ExA1 = fmaf(e1,ga.x,ExA1);  EyA1 = fmaf(e1,ga.y,EyA1);
      }
      {  // batch A, k = 2p+1
        float s0 = fmaf(AA0,ga.z, fmaf(BA0,ga.w, CA0));
        float s1 = fmaf(AA1,ga.z, fmaf(BA1,ga.w, CA1));
        float e0 = fexp2(s0), e1 = fexp2(s1);
        EA0 += e0;  ExA0 = fmaf(e0,ga.z,ExA0);  EyA0 = fmaf(e0,ga.w,EyA0);
        EA1 += e1;  ExA1 = fmaf(e1,ga.z,ExA1);  EyA1 = fmaf(e1,ga.w,EyA1);
      }
      {  // batch B, k = 2p
        float s0 = fmaf(AB0,gb.x, fmaf(BB0,gb.y, CB0));
        float s1 = fmaf(AB1,gb.x, fmaf(BB1,gb.y, CB1));
        float e0 = fexp2(s0), e1 = fexp2(s1);
        EB0 += e0;  ExB0 = fmaf(e0,gb.x,ExB0);  EyB0 = fmaf(e0,gb.y,EyB0);
        EB1 += e1;  ExB1 = fmaf(e1,gb.x,ExB1);  EyB1 = fmaf(e1,gb.y,EyB1);
      }
      {  // batch B, k = 2p+1
        float s0 = fmaf(AB0,gb.z, fmaf(BB0,gb.w, CB0));
        float s1 = fmaf(AB1,gb.z, fmaf(BB1,gb.w, CB1));
        float e0 = fexp2(s0), e1 = fexp2(s1);
        EB0 += e0;  ExB0 = fmaf(e0,gb.z,ExB0);  EyB0 = fmaf(e0,gb.w,EyB0);
        EB1 += e1;  ExB1 = fmaf(e1,gb.z,ExB1);  EyB1 = fmaf(e1,gb.w,EyB1);
      }
    }
    // epilogue: batch A
    {
      float r0 = frcp(EA0), r1 = frcp(EA1);
      float gx = fmaf(ExA0,r0, ExA1*r1);
      float gy = fmaf(EyA0,r0, EyA1*r1);
      #pragma unroll
      for (int m=1; m<64; m<<=1) {
        gx += __shfl_xor(gx, m, 64);
        gy += __shfl_xor(gy, m, 64);
      }
      gx *= 0.0078125f;  gy *= 0.0078125f;   // mean over 128 rows
      if (lane < DV)
        hbuf[(size_t)bA*80 + hoff + lane] = fmaf(gx, wv0, fmaf(gy, wv1, vb));
    }
    // epilogue: batch B
    {
      float r0 = frcp(EB0), r1 = frcp(EB1);
      float gx = fmaf(ExB0,r0, ExB1*r1);
      float gy = fmaf(EyB0,r0, EyB1*r1);
      #pragma unroll
      for (int m=1; m<64; m<<=1) {
        gx += __shfl_xor(gx, m, 64);
        gy += __shfl_xor(gy, m, 64);
      }
      gx *= 0.0078125f;  gy *= 0.0078125f;
      if (lane < DV)
        hbuf[(size_t)bB*80 + hoff + lane] = fmaf(gx, wv0, fmaf(gy, wv1, vb));
    }
  }
}

__global__ __launch_bounds__(256)
void attn_kernel(const float* __restrict__ state,
    const float* __restrict__ W_RT, const float* __restrict__ b_RT,
    const float* __restrict__ W_OB, const float* __restrict__ b_OB,
    const float* __restrict__ W_RS, const float* __restrict__ b_RS,
    const float* __restrict__ W_TG, const float* __restrict__ b_TG,
    float* __restrict__ hbuf)
{
  __shared__ float2 sg[4][2][128] __attribute__((aligned(16)));
  const int b0   = blockIdx.x * 4;    // 4 batches per block
  const int wave = threadIdx.x >> 6;
  const int lane = threadIdx.x & 63;

  const float* W;  const float* bb;
  if      (wave == 0) { W = W_RT; bb = b_RT; }
  else if (wave == 1) { W = W_OB; bb = b_OB; }
  else if (wave == 2) { W = W_RS; bb = b_RS; }
  else                { W = W_TG; bb = b_TG; }
  const int n0 = wave * 128;
  const int hoff = wave * 16;   // RT:0 OB:16 RS:32 TG:48..79

  if (wave < 3)
    branch_run<8 ,16,4>(state, b0, n0, W, bb,
                        &sg[wave][0][0], &sg[wave][1][0], hoff, hbuf, lane);
  else
    branch_run<16,32,4>(state, b0, n0, W, bb,
                        &sg[wave][0][0], &sg[wave][1][0], hoff, hbuf, lane);
}

// MLP: 80 -> 256 (tanh) -> 256 (tanh) -> 1.  (unchanged — measured ~10.6 us.)
// 16 batch rows per block, grid 256 = 1 block/CU. Thread t: unit-quad
// q=t>>2 (float4 coalesced weight loads), row-group rg=t&3 (rows
// 4rg..4rg+3). Depth-4 register prefetch, static i4&3 indexing.
__global__ __launch_bounds__(256, 1)
void mlp_kernel(const float* __restrict__ hbuf,
    const float* __restrict__ W1, const float* __restrict__ b1,
    const float* __restrict__ W2, const float* __restrict__ b2,
    const float* __restrict__ W3, const float* __restrict__ b3,
    float* __restrict__ out)
{
  __shared__ float sHin[16][84];
  __shared__ float sH1[16][260];
  __shared__ float sRed[4][16];
  const int t  = threadIdx.x;
  const int b0 = blockIdx.x * 16;
  const int q  = t >> 2;
  const int rg = t & 3;
  const int wave = t >> 6;

  for (int i = t; i < 16*80; i += 256) sHin[i/80][i%80] = hbuf[(size_t)b0*80 + i];
  __syncthreads();

  const float4* W1v = (const float4*)W1;
  const float4* W2v = (const float4*)W2;

  // ---- layer 1: 80 -> 256, tanh (depth-4 pipeline) ----
  float4 acc[4];
  {
    float4 bq = ((const float4*)b1)[q];
    acc[0]=bq; acc[1]=bq; acc[2]=bq; acc[3]=bq;
    float4 wb[4][4];
    #pragma unroll
    for (int p=0; p<4; ++p)
      #pragma unroll
      for (int jj=0; jj<4; ++jj) wb[p][jj] = W1v[(size_t)(4*p+jj)*64 + q];
    #pragma unroll 4
    for (int i4 = 0; i4 < 16; ++i4) {
      float4 w0=wb[i4&3][0], w1=wb[i4&3][1], w2=wb[i4&3][2], w3=wb[i4&3][3];
      #pragma unroll
      for (int jj=0; jj<4; ++jj) wb[i4&3][jj] = W1v[(size_t)((i4+4)*4+jj)*64 + q];
      #pragma unroll
      for (int r=0; r<4; ++r) {
        float4 h = *(const float4*)&sHin[4*rg+r][i4*4];
        acc[r] = fma4(h.x,w0, fma4(h.y,w1, fma4(h.z,w2, fma4(h.w,w3, acc[r]))));
      }
    }
    #pragma unroll
    for (int i4 = 16; i4 < 20; ++i4) {
      float4 w0=wb[i4&3][0], w1=wb[i4&3][1], w2=wb[i4&3][2], w3=wb[i4&3][3];
      #pragma unroll
      for (int r=0; r<4; ++r) {
        float4 h = *(const float4*)&sHin[4*rg+r][i4*4];
        acc[r] = fma4(h.x,w0, fma4(h.y,w1, fma4(h.z,w2, fma4(h.w,w3, acc[r]))));
      }
    }
  }
  #pragma unroll
  for (int r=0; r<4; ++r) {
    float4 o;
    o.x=tanh_fast(acc[r].x); o.y=tanh_fast(acc[r].y);
    o.z=tanh_fast(acc[r].z); o.w=tanh_fast(acc[r].w);
    *(float4*)&sH1[4*rg+r][4*q] = o;
  }
  __syncthreads();

  // ---- layer 2: 256 -> 256, tanh (depth-4 pipeline) ----
  float4 acc2[4];
  {
    float4 bq = ((const float4*)b2)[q];
    acc2[0]=bq; acc2[1]=bq; acc2[2]=bq; acc2[3]=bq;
    float4 wb[4][4];
    #pragma unroll
    for (int p=0; p<4; ++p)
      #pragma unroll
      for (int jj=0; jj<4; ++jj) wb[p][jj] = W2v[(size_t)(4*p+jj)*64 + q];
    #pragma unroll 4
    for (int i4 = 0; i4 < 60; ++i4) {
      float4 w0=wb[i4&3][0], w1=wb[i4&3][1], w2=wb[i4&3][2], w3=wb[i4&3][3];
      #pragma unroll
      for (int jj=0; jj<4; ++jj) wb[i4&3][jj] = W2v[(size_t)((i4+4)*4+jj)*64 + q];
      #pragma unroll
      for (int r=0; r<4; ++r) {
        float4 h = *(const float4*)&sH1[4*rg+r][i4*4];
        acc2[r] = fma4(h.x,w0, fma4(h.y,w1, fma4(h.z,w2, fma4(h.w,w3, acc2[r]))));
      }
    }
    #pragma unroll
    for (int i4 = 60; i4 < 64; ++i4) {
      float4 w0=wb[i4&3][0], w1=wb[i4&3][1], w2=wb[i4&3][2], w3=wb[i4&3][3];
      #pragma unroll
      for (int r=0; r<4; ++r) {
        float4 h = *(const float4*)&sH1[4*rg+r][i4*4];
        acc2[r] = fma4(h.x,w0, fma4(h.y,w1, fma4(h.z,w2, fma4(h.w,w3, acc2[r]))));
      }
    }
  }

  // ---- layer 3: 256 -> 1 ----
  float4 w3v = ((const float4*)W3)[q];
  float p[4];
  #pragma unroll
  for (int r=0; r<4; ++r) {
    p[r] = tanh_fast(acc2[r].x)*w3v.x + tanh_fast(acc2[r].y)*w3v.y
         + tanh_fast(acc2[r].z)*w3v.z + tanh_fast(acc2[r].w)*w3v.w;
  }
  #pragma unroll
  for (int m=4; m<64; m<<=1) {
    #pragma unroll
    for (int r=0; r<4; ++r) p[r] += __shfl_xor(p[r], m, 64);
  }
  if ((t & 63) == rg) {
    #pragma unroll
    for (int r=0; r<4; ++r) sRed[wave][4*rg + r] = p[r];
  }
  __syncthreads();
  if (t < 16)
    out[b0 + t] = sRed[0][t] + sRed[1][t] + sRed[2][t] + sRed[3][t] + b3[0];
}

extern "C" void kernel_launch(void* const* d_in, const int* in_sizes, int n_in,
                              void* d_out, int out_size, void* d_ws, size_t ws_size,
                              hipStream_t stream) {
  const float* state = (const float*)d_in[0];
  const float* W_RT = (const float*)d_in[5];
  const float* b_RT = (const float*)d_in[6];
  const float* W_OB = (const float*)d_in[7];
  const float* b_OB = (const float*)d_in[8];
  const float* W_RS = (const float*)d_in[9];
  const float* b_RS = (const float*)d_in[10];
  const float* W_TG = (const float*)d_in[11];
  const float* b_TG = (const float*)d_in[12];
  const float* W1 = (const float*)d_in[13];
  const float* b1 = (const float*)d_in[14];
  const float* W2 = (const float*)d_in[15];
  const float* b2 = (const float*)d_in[16];
  const float* W3 = (const float*)d_in[17];
  const float* b3 = (const float*)d_in[18];

  float* hbuf = (float*)d_ws;   // 4096 x 80 f32 = 1.31 MB

  attn_kernel<<<1024, 256, 0, stream>>>(state,
      W_RT, b_RT, W_OB, b_OB, W_RS, b_RS, W_TG, b_TG, hbuf);
  mlp_kernel<<<256, 256, 0, stream>>>(hbuf, W1, b1, W2, b2, W3, b3,
      (float*)d_out);
}